// Round 1
// baseline (1075.156 us; speedup 1.0000x reference)
//
#include <hip/hip_runtime.h>

// ---------------------------------------------------------------------------
// Model_644245095219: attention block (QKV proj + QK-RMSNorm + RoPE + causal
// GQA flash attention + out proj) for B=1, S=2048, H=4096, nH=32, nKV=8, d=128.
// Strategy: cast everything to f16, MFMA 16x16x32_f16 with fp32 accumulate.
// ---------------------------------------------------------------------------

typedef __attribute__((ext_vector_type(4))) float    f32x4;
typedef __attribute__((ext_vector_type(8))) _Float16 f16x8;
typedef __attribute__((ext_vector_type(4))) _Float16 f16x4;
typedef __attribute__((ext_vector_type(2))) _Float16 f16x2;

#define AS1 __attribute__((address_space(1)))
#define AS3 __attribute__((address_space(3)))

static __device__ __forceinline__ void gld_lds16(const void* g, void* l) {
  // async global->LDS, 16B per lane; LDS dest = wave-uniform base + lane*16
  __builtin_amdgcn_global_load_lds((AS1 void*)(g), (AS3 void*)(l), 16, 0, 0);
}

// ---------------- fp32 -> f16 convert (memory-bound) -----------------------
__global__ void f32_to_f16(const float* __restrict__ src,
                           _Float16* __restrict__ dst, int n4) {
  int i = blockIdx.x * blockDim.x + threadIdx.x;
  if (i >= n4) return;
  float4 v = ((const float4*)src)[i];
  f16x4 o = {(_Float16)v.x, (_Float16)v.y, (_Float16)v.z, (_Float16)v.w};
  ((f16x4*)dst)[i] = o;
}

// ---------------- GEMM: C[M,N] = A[M,K] @ B[N,K]^T  (f16 in, f32 out) ------
// 128x128 tile / block of 256 threads (4 waves, 2x2), BK=32, m97-style.
__global__ __launch_bounds__(256) void gemm_bt(
    const _Float16* __restrict__ A, const _Float16* __restrict__ B,
    float* __restrict__ C, int M, int N, int K) {
  __shared__ _Float16 lA[128 * 32];  // row-major [128][32]
  __shared__ _Float16 lB[128 * 32];
  const int tid  = threadIdx.x;
  const int wave = tid >> 6, lane = tid & 63;
  const int quad = lane >> 4, l16 = lane & 15;
  const int wr = wave >> 1, wc = wave & 1;  // 2x2 wave grid, 64x64 per wave
  const int m0 = blockIdx.y * 128, n0 = blockIdx.x * 128;

  f32x4 acc[4][4];
#pragma unroll
  for (int i = 0; i < 4; i++)
#pragma unroll
    for (int j = 0; j < 4; j++) acc[i][j] = f32x4{0.f, 0.f, 0.f, 0.f};

  for (int k0 = 0; k0 < K; k0 += 32) {
    __syncthreads();  // previous iter's LDS reads done before overwrite
#pragma unroll
    for (int j = 0; j < 2; ++j) {
      int c0 = wave * 128 + j * 64;  // wave-uniform base chunk
      int c  = c0 + lane;            // chunk: row=c>>2, kchunk=c&3 (8 elems)
      const _Float16* gA = A + (size_t)(m0 + (c >> 2)) * K + k0 + (c & 3) * 8;
      const _Float16* gB = B + (size_t)(n0 + (c >> 2)) * K + k0 + (c & 3) * 8;
      gld_lds16(gA, &lA[c0 * 8]);
      gld_lds16(gB, &lB[c0 * 8]);
    }
    __builtin_amdgcn_s_waitcnt(0);
    __syncthreads();

    f16x8 af[4], bfr[4];
#pragma unroll
    for (int mi = 0; mi < 4; mi++)
      af[mi] = *(const f16x8*)&lA[(wr * 64 + mi * 16 + l16) * 32 + quad * 8];
#pragma unroll
    for (int ni = 0; ni < 4; ni++)
      bfr[ni] = *(const f16x8*)&lB[(wc * 64 + ni * 16 + l16) * 32 + quad * 8];
#pragma unroll
    for (int mi = 0; mi < 4; mi++)
#pragma unroll
      for (int ni = 0; ni < 4; ni++)
        acc[mi][ni] = __builtin_amdgcn_mfma_f32_16x16x32_f16(
            af[mi], bfr[ni], acc[mi][ni], 0, 0, 0);
  }
  // epilogue: C/D layout col=l16, row=quad*4+reg
#pragma unroll
  for (int mi = 0; mi < 4; mi++) {
    int m = m0 + wr * 64 + mi * 16 + quad * 4;
#pragma unroll
    for (int ni = 0; ni < 4; ni++) {
      int n = n0 + wc * 64 + ni * 16 + l16;
      float* cp = C + (size_t)m * N + n;
#pragma unroll
      for (int r = 0; r < 4; r++) cp[(size_t)r * N] = acc[mi][ni][r];
    }
  }
}

// ---------------- per-head RMSNorm + RoPE, one wave per (s, head) ----------
// raw: [S, nh*128] f32 -> out: [nh][S][128] f16
__global__ void norm_rope(const float* __restrict__ raw,
                          const float* __restrict__ w,
                          const float* __restrict__ cosb,
                          const float* __restrict__ sinb,
                          const int* __restrict__ pos,
                          _Float16* __restrict__ out, int nh_log2, int S) {
  int gt = blockIdx.x * blockDim.x + threadIdx.x;
  int wid = gt >> 6, lane = gt & 63;
  int h = wid & ((1 << nh_log2) - 1);
  int s = wid >> nh_log2;
  const float* x = raw + ((size_t)s << (nh_log2 + 7)) + h * 128;
  float2 v = *(const float2*)&x[lane * 2];
  float ss = v.x * v.x + v.y * v.y;
#pragma unroll
  for (int m = 1; m < 64; m <<= 1) ss += __shfl_xor(ss, m);
  float inv = rsqrtf(ss * (1.f / 128.f) + 1e-6f);
  int p = pos[s];
  float n0 = v.x * inv * w[lane * 2];
  float n1 = v.y * inv * w[lane * 2 + 1];
  // rotate_half: i<64 pairs with i+64 (negated partner); i>=64 with i-64
  float p0 = __shfl_xor(n0, 32);
  float p1 = __shfl_xor(n1, 32);
  float r0 = (lane < 32) ? -p0 : p0;
  float r1 = (lane < 32) ? -p1 : p1;
  float c0 = cosb[p * 128 + lane * 2], c1 = cosb[p * 128 + lane * 2 + 1];
  float s0 = sinb[p * 128 + lane * 2], s1 = sinb[p * 128 + lane * 2 + 1];
  f16x2 o;
  o.x = (_Float16)(n0 * c0 + r0 * s0);
  o.y = (_Float16)(n1 * c1 + r1 * s1);
  *(f16x2*)&out[((size_t)h * S + s) * 128 + lane * 2] = o;
}

// ---------------- V transpose+convert: [S,1024] f32 -> [1024][S] f16 -------
__global__ __launch_bounds__(256) void v_trans(const float* __restrict__ vraw,
                                               _Float16* __restrict__ vt,
                                               int S) {
  __shared__ _Float16 tile[64][72];
  int s0 = blockIdx.x * 64, c0 = blockIdx.y * 64;
  int t = threadIdx.x;
  int r = t >> 2, cq = (t & 3) * 16;
  const float* src = vraw + (size_t)(s0 + r) * 1024 + c0 + cq;
#pragma unroll
  for (int j = 0; j < 4; j++) {
    float4 v = *(const float4*)&src[j * 4];
    tile[r][cq + j * 4 + 0] = (_Float16)v.x;
    tile[r][cq + j * 4 + 1] = (_Float16)v.y;
    tile[r][cq + j * 4 + 2] = (_Float16)v.z;
    tile[r][cq + j * 4 + 3] = (_Float16)v.w;
  }
  __syncthreads();
  int orow = t >> 2, sq = (t & 3) * 16;
  _Float16* dst = vt + (size_t)(c0 + orow) * S + s0 + sq;
  f16x8 a, b;
#pragma unroll
  for (int j = 0; j < 8; j++) a[j] = tile[sq + j][orow];
#pragma unroll
  for (int j = 0; j < 8; j++) b[j] = tile[sq + 8 + j][orow];
  *(f16x8*)&dst[0] = a;
  *(f16x8*)&dst[8] = b;
}

// ---------------- causal GQA flash attention -------------------------------
// Qh: [32][S][128] f16 (normed+roped), Kh: [8][S][128] f16, Vt: [8][128][S]
// Oout: [S][4096] f16.  One wave = 16 q rows; K-step = 32; no LDS/barriers.
// QK^T computed transposed (D[kcol][q]) so per-q softmax stats are per-lane
// scalars; P C-layout -> B-operand layout done with register shuffles.
__global__ __launch_bounds__(256) void flash_attn(
    const _Float16* __restrict__ Qh, const _Float16* __restrict__ Kh,
    const _Float16* __restrict__ Vt, _Float16* __restrict__ Oout, int S) {
  const int h = blockIdx.y;
  const int kvh = h >> 2;  // n_rep = 4
  const int wave = threadIdx.x >> 6, lane = threadIdx.x & 63;
  const int quad = lane >> 4, l16 = lane & 15;
  const int qb = (gridDim.x - 1 - blockIdx.x) * 64;  // heavy blocks first
  const int wq = qb + wave * 16;
  const _Float16* Q = Qh + ((size_t)h * S + wq) * 128;
  const _Float16* K = Kh + (size_t)kvh * S * 128;
  const _Float16* V = Vt + (size_t)kvh * 128 * S;

  f16x8 qf[4];  // B-operand: n=l16 (q row), k = kq*32+quad*8+j
#pragma unroll
  for (int kq = 0; kq < 4; kq++)
    qf[kq] = *(const f16x8*)&Q[(size_t)l16 * 128 + kq * 32 + quad * 8];

  f32x4 o[8];  // O^T acc: d = t*16+quad*4+r, q = l16
#pragma unroll
  for (int t = 0; t < 8; t++) o[t] = f32x4{0.f, 0.f, 0.f, 0.f};
  float m_i = -__builtin_inff(), l_i = 0.f;
  const int q_row = wq + l16;
  const float scale = 0.08838834764831845f;  // 1/sqrt(128)

  const int ktend = (wq + 15) / 32;  // inclusive; later tiles fully masked
  for (int kt = 0; kt <= ktend; ++kt) {
    // scores^T: D[kcol][q]; A = K rows (m=kcol), B = Q^T (n=q)
    f32x4 sc[2];
    sc[0] = f32x4{0.f, 0.f, 0.f, 0.f};
    sc[1] = f32x4{0.f, 0.f, 0.f, 0.f};
#pragma unroll
    for (int mt = 0; mt < 2; mt++)
#pragma unroll
      for (int kq = 0; kq < 4; kq++) {
        f16x8 kf = *(const f16x8*)&K[(size_t)(kt * 32 + mt * 16 + l16) * 128 +
                                     kq * 32 + quad * 8];
        sc[mt] =
            __builtin_amdgcn_mfma_f32_16x16x32_f16(kf, qf[kq], sc[mt], 0, 0, 0);
      }
    // scale + causal mask; all 8 values in this lane share q = q_row
    float p[2][4];
    float tmax = -__builtin_inff();
#pragma unroll
    for (int mt = 0; mt < 2; mt++)
#pragma unroll
      for (int r = 0; r < 4; r++) {
        int kcol = kt * 32 + mt * 16 + quad * 4 + r;
        float v = sc[mt][r] * scale;
        v = (kcol <= q_row) ? v : -__builtin_inff();
        p[mt][r] = v;
        tmax = fmaxf(tmax, v);
      }
    tmax = fmaxf(tmax, __shfl_xor(tmax, 16));
    tmax = fmaxf(tmax, __shfl_xor(tmax, 32));
    float m_new = fmaxf(m_i, tmax);
    float alpha = __expf(m_i - m_new);  // first iter: exp(-inf)=0
    float rsum = 0.f;
#pragma unroll
    for (int mt = 0; mt < 2; mt++)
#pragma unroll
      for (int r = 0; r < 4; r++) {
        float e = __expf(p[mt][r] - m_new);
        p[mt][r] = e;
        rsum += e;
      }
    rsum += __shfl_xor(rsum, 16);
    rsum += __shfl_xor(rsum, 32);
    l_i = l_i * alpha + rsum;
    m_i = m_new;
#pragma unroll
    for (int t = 0; t < 8; t++) o[t] *= alpha;
    // Build P B-operand frag: need P^T[kcol=quad*8+j][q=l16].
    // Source lane: quad' = 2*(quad&1)+(j>>2), same l16; value p[quad>>1][j&3].
    union {
      _Float16 hh[8];
      f16x8 v;
    } pf;
#pragma unroll
    for (int j = 0; j < 8; j++) {
      int src = (2 * (quad & 1) + (j >> 2)) * 16 + l16;
      float v0 = __shfl(p[0][j & 3], src);
      float v1 = __shfl(p[1][j & 3], src);
      pf.hh[j] = (_Float16)((quad < 2) ? v0 : v1);
    }
    // PV: O^T += V^T @ P^T ; A = Vt rows (m=d), B = pf
#pragma unroll
    for (int t = 0; t < 8; t++) {
      f16x8 vf = *(const f16x8*)&V[(size_t)(t * 16 + l16) * S + kt * 32 +
                                   quad * 8];
      o[t] = __builtin_amdgcn_mfma_f32_16x16x32_f16(vf, pf.v, o[t], 0, 0, 0);
    }
  }
  float invl = 1.f / l_i;
  _Float16* op = Oout + (size_t)q_row * 4096 + h * 128 + quad * 4;
#pragma unroll
  for (int t = 0; t < 8; t++)
#pragma unroll
    for (int r = 0; r < 4; r++)
      op[t * 16 + r] = (_Float16)(o[t][r] * invl);
}

// ---------------------------------------------------------------------------
extern "C" void kernel_launch(void* const* d_in, const int* in_sizes, int n_in,
                              void* d_out, int out_size, void* d_ws,
                              size_t ws_size, hipStream_t stream) {
  const int S = 2048, H = 4096, NH = 32, NKV = 8, D = 128;
  const float* hs   = (const float*)d_in[0];
  const int*   pos  = (const int*)d_in[1];
  const float* Wq   = (const float*)d_in[2];
  const float* Wk   = (const float*)d_in[3];
  const float* Wv   = (const float*)d_in[4];
  const float* Wo   = (const float*)d_in[5];
  const float* qw   = (const float*)d_in[6];
  const float* kw   = (const float*)d_in[7];
  const float* cosb = (const float*)d_in[8];
  const float* sinb = (const float*)d_in[9];
  float* out = (float*)d_out;

  // workspace layout (bytes); total 142,606,336
  char* ws = (char*)d_ws;
  _Float16* hid_bf  = (_Float16*)(ws + 0);          // 16.78 MB [S][H]
  _Float16* wq_bf   = (_Float16*)(ws + 16777216);   // 33.55 MB [4096][4096]
  _Float16* wk_bf   = (_Float16*)(ws + 50331648);   //  8.39 MB [1024][4096]
  _Float16* wv_bf   = (_Float16*)(ws + 58720256);   //  8.39 MB
  float*    q_raw   = (float*)(ws + 67108864);      // 33.55 MB [S][4096]
  float*    k_raw   = (float*)(ws + 100663296);     //  8.39 MB [S][1024]
  float*    v_raw   = (float*)(ws + 109051904);     //  8.39 MB
  _Float16* q_bf    = (_Float16*)(ws + 117440512);  // 16.78 MB [32][S][128]
  _Float16* k_bf    = (_Float16*)(ws + 134217728);  //  4.19 MB [8][S][128]
  _Float16* v_t     = (_Float16*)(ws + 138412032);  //  4.19 MB [1024][S]
  _Float16* attn_bf = (_Float16*)(ws + 67108864);   // alias q_raw (dead)
  _Float16* wo_bf   = (_Float16*)(ws + 16777216);   // alias wq_bf (dead)

  // fp32 -> f16 converts
  f32_to_f16<<<(S * H / 4 + 255) / 256, 256, 0, stream>>>(hs, hid_bf, S * H / 4);
  f32_to_f16<<<(H * H / 4 + 255) / 256, 256, 0, stream>>>(Wq, wq_bf, H * H / 4);
  f32_to_f16<<<(NKV * D * H / 4 + 255) / 256, 256, 0, stream>>>(
      Wk, wk_bf, NKV * D * H / 4);
  f32_to_f16<<<(NKV * D * H / 4 + 255) / 256, 256, 0, stream>>>(
      Wv, wv_bf, NKV * D * H / 4);

  // projections
  gemm_bt<<<dim3(NH * D / 128, S / 128), 256, 0, stream>>>(hid_bf, wq_bf, q_raw,
                                                           S, NH * D, H);
  gemm_bt<<<dim3(NKV * D / 128, S / 128), 256, 0, stream>>>(hid_bf, wk_bf,
                                                            k_raw, S, NKV * D, H);
  gemm_bt<<<dim3(NKV * D / 128, S / 128), 256, 0, stream>>>(hid_bf, wv_bf,
                                                            v_raw, S, NKV * D, H);
  // Wo convert (into wq_bf slot, now dead)
  f32_to_f16<<<(H * H / 4 + 255) / 256, 256, 0, stream>>>(Wo, wo_bf, H * H / 4);

  // per-head RMSNorm + RoPE (q: nh=32 -> log2 5; k: nh=8 -> log2 3)
  norm_rope<<<S * NH / 4, 256, 0, stream>>>(q_raw, qw, cosb, sinb, pos, q_bf, 5,
                                            S);
  norm_rope<<<S * NKV / 4, 256, 0, stream>>>(k_raw, kw, cosb, sinb, pos, k_bf,
                                             3, S);
  v_trans<<<dim3(S / 64, NKV * D / 64), 256, 0, stream>>>(v_raw, v_t, S);

  // causal flash attention -> attn_bf [S][4096] f16
  flash_attn<<<dim3(S / 64, NH), 256, 0, stream>>>(q_bf, k_bf, v_t, attn_bf, S);

  // output projection -> d_out fp32
  gemm_bt<<<dim3(H / 128, S / 128), 256, 0, stream>>>(attn_bf, wo_bf, out, S, H,
                                                      H);
}

// Round 2
// 933.096 us; speedup vs baseline: 1.1522x; 1.1522x over previous
//
#include <hip/hip_runtime.h>

// ---------------------------------------------------------------------------
// Model_644245095219: attention block (QKV proj + QK-RMSNorm + RoPE + causal
// GQA flash attention + out proj) for B=1, S=2048, H=4096, nH=32, nKV=8, d=128.
// f16 MFMA path. R1: fixed-M flash softmax (no running max; |score|<=sqrt(128)
// by Cauchy-Schwarz after RMSNorm+RoPE), LDS-based P transform instead of 16
// ds_bpermutes, fused QKV projection GEMM.
// ---------------------------------------------------------------------------

typedef __attribute__((ext_vector_type(4))) float    f32x4;
typedef __attribute__((ext_vector_type(8))) _Float16 f16x8;
typedef __attribute__((ext_vector_type(4))) _Float16 f16x4;
typedef __attribute__((ext_vector_type(2))) _Float16 f16x2;

#define AS1 __attribute__((address_space(1)))
#define AS3 __attribute__((address_space(3)))

static __device__ __forceinline__ void gld_lds16(const void* g, void* l) {
  __builtin_amdgcn_global_load_lds((AS1 void*)(g), (AS3 void*)(l), 16, 0, 0);
}

// ---------------- fp32 -> f16 convert (memory-bound) -----------------------
__global__ void f32_to_f16(const float* __restrict__ src,
                           _Float16* __restrict__ dst, int n4) {
  int i = blockIdx.x * blockDim.x + threadIdx.x;
  if (i >= n4) return;
  float4 v = ((const float4*)src)[i];
  f16x4 o = {(_Float16)v.x, (_Float16)v.y, (_Float16)v.z, (_Float16)v.w};
  ((f16x4*)dst)[i] = o;
}

// ---------------- GEMM: C[M,N] = A[M,K] @ B[N,K]^T  (f16 in, f32 out) ------
__global__ __launch_bounds__(256) void gemm_bt(
    const _Float16* __restrict__ A, const _Float16* __restrict__ B,
    float* __restrict__ C, int M, int N, int K) {
  __shared__ _Float16 lA[128 * 32];
  __shared__ _Float16 lB[128 * 32];
  const int tid  = threadIdx.x;
  const int wave = tid >> 6, lane = tid & 63;
  const int quad = lane >> 4, l16 = lane & 15;
  const int wr = wave >> 1, wc = wave & 1;
  const int m0 = blockIdx.y * 128, n0 = blockIdx.x * 128;

  f32x4 acc[4][4];
#pragma unroll
  for (int i = 0; i < 4; i++)
#pragma unroll
    for (int j = 0; j < 4; j++) acc[i][j] = f32x4{0.f, 0.f, 0.f, 0.f};

  for (int k0 = 0; k0 < K; k0 += 32) {
    __syncthreads();
#pragma unroll
    for (int j = 0; j < 2; ++j) {
      int c0 = wave * 128 + j * 64;
      int c  = c0 + lane;
      const _Float16* gA = A + (size_t)(m0 + (c >> 2)) * K + k0 + (c & 3) * 8;
      const _Float16* gB = B + (size_t)(n0 + (c >> 2)) * K + k0 + (c & 3) * 8;
      gld_lds16(gA, &lA[c0 * 8]);
      gld_lds16(gB, &lB[c0 * 8]);
    }
    __builtin_amdgcn_s_waitcnt(0);
    __syncthreads();

    f16x8 af[4], bfr[4];
#pragma unroll
    for (int mi = 0; mi < 4; mi++)
      af[mi] = *(const f16x8*)&lA[(wr * 64 + mi * 16 + l16) * 32 + quad * 8];
#pragma unroll
    for (int ni = 0; ni < 4; ni++)
      bfr[ni] = *(const f16x8*)&lB[(wc * 64 + ni * 16 + l16) * 32 + quad * 8];
#pragma unroll
    for (int mi = 0; mi < 4; mi++)
#pragma unroll
      for (int ni = 0; ni < 4; ni++)
        acc[mi][ni] = __builtin_amdgcn_mfma_f32_16x16x32_f16(
            af[mi], bfr[ni], acc[mi][ni], 0, 0, 0);
  }
#pragma unroll
  for (int mi = 0; mi < 4; mi++) {
    int m = m0 + wr * 64 + mi * 16 + quad * 4;
#pragma unroll
    for (int ni = 0; ni < 4; ni++) {
      int n = n0 + wc * 64 + ni * 16 + l16;
      float* cp = C + (size_t)m * N + n;
#pragma unroll
      for (int r = 0; r < 4; r++) cp[(size_t)r * N] = acc[mi][ni][r];
    }
  }
}

// ---------------- per-head RMSNorm + RoPE, one wave per (s, head) ----------
// raw: [S, row_stride] f32, head block at col_off + h*128 -> out [nh][S][128]
__global__ void norm_rope(const float* __restrict__ raw, int row_stride,
                          int col_off, const float* __restrict__ w,
                          const float* __restrict__ cosb,
                          const float* __restrict__ sinb,
                          const int* __restrict__ pos,
                          _Float16* __restrict__ out, int nh_log2, int S) {
  int gt = blockIdx.x * blockDim.x + threadIdx.x;
  int wid = gt >> 6, lane = gt & 63;
  int h = wid & ((1 << nh_log2) - 1);
  int s = wid >> nh_log2;
  const float* x = raw + (size_t)s * row_stride + col_off + h * 128;
  float2 v = *(const float2*)&x[lane * 2];
  float ss = v.x * v.x + v.y * v.y;
#pragma unroll
  for (int m = 1; m < 64; m <<= 1) ss += __shfl_xor(ss, m);
  float inv = rsqrtf(ss * (1.f / 128.f) + 1e-6f);
  int p = pos[s];
  float n0 = v.x * inv * w[lane * 2];
  float n1 = v.y * inv * w[lane * 2 + 1];
  float p0 = __shfl_xor(n0, 32);
  float p1 = __shfl_xor(n1, 32);
  float r0 = (lane < 32) ? -p0 : p0;
  float r1 = (lane < 32) ? -p1 : p1;
  float c0 = cosb[p * 128 + lane * 2], c1 = cosb[p * 128 + lane * 2 + 1];
  float s0 = sinb[p * 128 + lane * 2], s1 = sinb[p * 128 + lane * 2 + 1];
  f16x2 o;
  o.x = (_Float16)(n0 * c0 + r0 * s0);
  o.y = (_Float16)(n1 * c1 + r1 * s1);
  *(f16x2*)&out[((size_t)h * S + s) * 128 + lane * 2] = o;
}

// ---------------- V transpose+convert: [S,*] f32 cols -> [1024][S] f16 -----
__global__ __launch_bounds__(256) void v_trans(const float* __restrict__ vraw,
                                               int row_stride,
                                               _Float16* __restrict__ vt,
                                               int S) {
  __shared__ _Float16 tile[64][72];
  int s0 = blockIdx.x * 64, c0 = blockIdx.y * 64;
  int t = threadIdx.x;
  int r = t >> 2, cq = (t & 3) * 16;
  const float* src = vraw + (size_t)(s0 + r) * row_stride + c0 + cq;
#pragma unroll
  for (int j = 0; j < 4; j++) {
    float4 v = *(const float4*)&src[j * 4];
    tile[r][cq + j * 4 + 0] = (_Float16)v.x;
    tile[r][cq + j * 4 + 1] = (_Float16)v.y;
    tile[r][cq + j * 4 + 2] = (_Float16)v.z;
    tile[r][cq + j * 4 + 3] = (_Float16)v.w;
  }
  __syncthreads();
  int orow = t >> 2, sq = (t & 3) * 16;
  _Float16* dst = vt + (size_t)(c0 + orow) * S + s0 + sq;
  f16x8 a, b;
#pragma unroll
  for (int j = 0; j < 8; j++) a[j] = tile[sq + j][orow];
#pragma unroll
  for (int j = 0; j < 8; j++) b[j] = tile[sq + 8 + j][orow];
  *(f16x8*)&dst[0] = a;
  *(f16x8*)&dst[8] = b;
}

// ---------------- causal GQA flash attention (fixed-M softmax) -------------
// Qh: [32][S][128] f16, Kh: [8][S][128] f16, Vt: [8][128][S] f16
// Oout: [S][4096] f16. One wave = 16 q rows, K-step 32.
// |score| <= sqrt(128) (RMSNorm gives |q|=|k|=sqrt(128); RoPE is a rotation),
// so exp(s - M) with fixed M=5 never overflows and the row-max P never
// flushes to 0 in f16. No running max => K-tiles independent (ILP), no alpha.
// P transform C-layout -> B-operand via per-wave LDS patch (2 write_b64 +
// 1 read_b128), replacing 16 ds_bpermutes.
__global__ __launch_bounds__(256) void flash_attn(
    const _Float16* __restrict__ Qh, const _Float16* __restrict__ Kh,
    const _Float16* __restrict__ Vt, _Float16* __restrict__ Oout, int S) {
  __shared__ _Float16 plds[4][16][40];  // per-wave private patch, stride 40
  const int h = blockIdx.y;
  const int kvh = h >> 2;  // n_rep = 4
  const int wave = threadIdx.x >> 6, lane = threadIdx.x & 63;
  const int quad = lane >> 4, l16 = lane & 15;
  const int qb = (gridDim.x - 1 - blockIdx.x) * 64;  // heavy blocks first
  const int wq = qb + wave * 16;
  const _Float16* Q = Qh + ((size_t)h * S + wq) * 128;
  const _Float16* K = Kh + (size_t)kvh * S * 128;
  const _Float16* V = Vt + (size_t)kvh * 128 * S;

  f16x8 qf[4];  // B-operand: n=l16 (q row), k = kq*32+quad*8+j
#pragma unroll
  for (int kq = 0; kq < 4; kq++)
    qf[kq] = *(const f16x8*)&Q[(size_t)l16 * 128 + kq * 32 + quad * 8];

  f32x4 o[8];  // O^T acc: d = t*16+quad*4+r, q = l16
#pragma unroll
  for (int t = 0; t < 8; t++) o[t] = f32x4{0.f, 0.f, 0.f, 0.f};
  float l_i = 0.f;
  const int q_row = wq + l16;
  const float scale = 0.08838834764831845f;  // 1/sqrt(128)
  const float M = 5.0f;

  const int ktend = (wq + 15) >> 5;
  for (int kt = 0; kt <= ktend; ++kt) {
    // scores^T: D[kcol][q]; A = K rows (m=kcol), B = Q^T (n=q)
    f32x4 sc[2];
    sc[0] = f32x4{0.f, 0.f, 0.f, 0.f};
    sc[1] = f32x4{0.f, 0.f, 0.f, 0.f};
#pragma unroll
    for (int mt = 0; mt < 2; mt++)
#pragma unroll
      for (int kq = 0; kq < 4; kq++) {
        f16x8 kf = *(const f16x8*)&K[(size_t)(kt * 32 + mt * 16 + l16) * 128 +
                                     kq * 32 + quad * 8];
        sc[mt] =
            __builtin_amdgcn_mfma_f32_16x16x32_f16(kf, qf[kq], sc[mt], 0, 0, 0);
      }
    // p = exp(s*scale - M), causal-masked; this lane: q=q_row fixed,
    // kcol = kt*32 + mt*16 + quad*4 + r
    float p[2][4];
    float rsum = 0.f;
#pragma unroll
    for (int mt = 0; mt < 2; mt++)
#pragma unroll
      for (int r = 0; r < 4; r++) {
        int kcol = kt * 32 + mt * 16 + quad * 4 + r;
        float e = __expf(fmaf(sc[mt][r], scale, -M));
        e = (kcol <= q_row) ? e : 0.f;
        p[mt][r] = e;
        rsum += e;
      }
    rsum += __shfl_xor(rsum, 16);
    rsum += __shfl_xor(rsum, 32);
    l_i += rsum;
    // C-layout -> B-operand layout via per-wave LDS patch ([q][kcol], pad 40)
    f16x4 pk0 = {(_Float16)p[0][0], (_Float16)p[0][1], (_Float16)p[0][2],
                 (_Float16)p[0][3]};
    f16x4 pk1 = {(_Float16)p[1][0], (_Float16)p[1][1], (_Float16)p[1][2],
                 (_Float16)p[1][3]};
    *(f16x4*)&plds[wave][l16][quad * 4] = pk0;
    *(f16x4*)&plds[wave][l16][16 + quad * 4] = pk1;
    f16x8 pf = *(const f16x8*)&plds[wave][l16][quad * 8];
    // PV: O^T += V^T @ P^T ; A = Vt rows (m=d), B = pf (n=q, k=kcol)
#pragma unroll
    for (int t = 0; t < 8; t++) {
      f16x8 vf = *(const f16x8*)&V[(size_t)(t * 16 + l16) * S + kt * 32 +
                                   quad * 8];
      o[t] = __builtin_amdgcn_mfma_f32_16x16x32_f16(vf, pf, o[t], 0, 0, 0);
    }
  }
  float invl = 1.f / l_i;
  _Float16* op = Oout + (size_t)q_row * 4096 + h * 128 + quad * 4;
#pragma unroll
  for (int t = 0; t < 8; t++) {
    f16x4 ov = {(_Float16)(o[t][0] * invl), (_Float16)(o[t][1] * invl),
                (_Float16)(o[t][2] * invl), (_Float16)(o[t][3] * invl)};
    *(f16x4*)&op[t * 16] = ov;
  }
}

// ---------------------------------------------------------------------------
extern "C" void kernel_launch(void* const* d_in, const int* in_sizes, int n_in,
                              void* d_out, int out_size, void* d_ws,
                              size_t ws_size, hipStream_t stream) {
  const int S = 2048, H = 4096, NH = 32, NKV = 8, D = 128;
  const int NQKV = NH * D + 2 * NKV * D;  // 6144
  const float* hs   = (const float*)d_in[0];
  const int*   pos  = (const int*)d_in[1];
  const float* Wq   = (const float*)d_in[2];
  const float* Wk   = (const float*)d_in[3];
  const float* Wv   = (const float*)d_in[4];
  const float* Wo   = (const float*)d_in[5];
  const float* qw   = (const float*)d_in[6];
  const float* kw   = (const float*)d_in[7];
  const float* cosb = (const float*)d_in[8];
  const float* sinb = (const float*)d_in[9];
  float* out = (float*)d_out;

  // workspace layout (bytes); total 142,606,336
  char* ws = (char*)d_ws;
  _Float16* wqkv    = (_Float16*)(ws + 0);          // 50.33 MB [6144][4096]
  _Float16* hid_bf  = (_Float16*)(ws + 50331648);   // 16.78 MB [S][H]
  float*    qkv_raw = (float*)(ws + 67108864);      // 50.33 MB [S][6144] f32
  _Float16* q_bf    = (_Float16*)(ws + 117440512);  // 16.78 MB [32][S][128]
  _Float16* k_bf    = (_Float16*)(ws + 134217728);  //  4.19 MB [8][S][128]
  _Float16* v_t     = (_Float16*)(ws + 138412032);  //  4.19 MB [1024][S]
  _Float16* attn_bf = (_Float16*)(ws + 67108864);   // alias qkv_raw (dead)
  _Float16* wo_bf   = (_Float16*)(ws + 0);          // alias wqkv (dead)

  // fp32 -> f16 converts (QKV weights fused into one [6144][4096] buffer)
  f32_to_f16<<<(S * H / 4 + 255) / 256, 256, 0, stream>>>(hs, hid_bf, S * H / 4);
  f32_to_f16<<<(H * H / 4 + 255) / 256, 256, 0, stream>>>(Wq, wqkv, H * H / 4);
  f32_to_f16<<<(NKV * D * H / 4 + 255) / 256, 256, 0, stream>>>(
      Wk, wqkv + (size_t)H * H, NKV * D * H / 4);
  f32_to_f16<<<(NKV * D * H / 4 + 255) / 256, 256, 0, stream>>>(
      Wv, wqkv + (size_t)(H + NKV * D) * H, NKV * D * H / 4);

  // fused QKV projection: [2048][6144] = hid @ wqkv^T
  gemm_bt<<<dim3(NQKV / 128, S / 128), 256, 0, stream>>>(hid_bf, wqkv, qkv_raw,
                                                         S, NQKV, H);
  // Wo convert into wqkv slot (dead after QKV gemm)
  f32_to_f16<<<(H * H / 4 + 255) / 256, 256, 0, stream>>>(Wo, wo_bf, H * H / 4);

  // per-head RMSNorm + RoPE
  norm_rope<<<S * NH / 4, 256, 0, stream>>>(qkv_raw, NQKV, 0, qw, cosb, sinb,
                                            pos, q_bf, 5, S);
  norm_rope<<<S * NKV / 4, 256, 0, stream>>>(qkv_raw, NQKV, H, kw, cosb, sinb,
                                             pos, k_bf, 3, S);
  v_trans<<<dim3(S / 64, NKV * D / 64), 256, 0, stream>>>(
      qkv_raw + (size_t)(H + NKV * D), NQKV, v_t, S);

  // causal flash attention -> attn_bf [S][4096] f16 (into dead qkv_raw slot)
  flash_attn<<<dim3(S / 64, NH), 256, 0, stream>>>(q_bf, k_bf, v_t, attn_bf, S);

  // output projection -> d_out fp32
  gemm_bt<<<dim3(H / 128, S / 128), 256, 0, stream>>>(attn_bf, wo_bf, out, S, H,
                                                      H);
}